// Round 1
// baseline (581.801 us; speedup 1.0000x reference)
//
#include <hip/hip_runtime.h>
#include <math.h>

#define NW 2048
#define MP 64
#define KL 32
#define DF 512

// ---------------------------------------------------------------------------
// K1: dots[n][m][k] = sum_d data[n][m][d] * W[k][d]
// grid 2048 (1 block/word), block 256 (4 waves). Wave w handles k-range w*8..w*8+7,
// lane m = tid&63 handles one row. W loads are wave-uniform -> scalar loads.
// ---------------------------------------------------------------------------
__global__ __launch_bounds__(256, 4) void k_dots(const float* __restrict__ data,
                                                 const float* __restrict__ W,
                                                 float* __restrict__ dots) {
    __shared__ float dt[64][33];  // +1 pad: conflict-free scattered writes
    const int n = blockIdx.x;
    const int tid = threadIdx.x;
    const int m = tid & 63;
    const int k0 = __builtin_amdgcn_readfirstlane((tid >> 6) << 3);

    const float4* d4 = (const float4*)(data + (size_t)(n * 64 + m) * 512);
    const float4* w4 = (const float4*)W;

    float acc[8];
#pragma unroll
    for (int i = 0; i < 8; ++i) acc[i] = 0.f;

    for (int dq = 0; dq < 128; ++dq) {
        float4 dv = d4[dq];
#pragma unroll
        for (int kk = 0; kk < 8; ++kk) {
            float4 wv = w4[(k0 + kk) * 128 + dq];
            acc[kk] += dv.x * wv.x + dv.y * wv.y + dv.z * wv.z + dv.w * wv.w;
        }
    }
#pragma unroll
    for (int kk = 0; kk < 8; ++kk) dt[m][k0 + kk] = acc[kk];
    __syncthreads();
    float* outp = dots + (size_t)n * 2048;
    for (int q = tid; q < 2048; q += 256) outp[q] = dt[q >> 5][q & 31];
}

// ---------------------------------------------------------------------------
// K2: per-word scaled linear-space forward-backward.
//   E = exp(T) (cols+rows in regs). Beta pass stores Y[i] = B[i]*gd[i] (normalized)
//   to LDS; alpha pass fuses p1 (-> Pdiff overwrites dots in ws) and the p2
//   rank-1 accumulation S += x y^T / Z.  dT partial = pair-hist - E.*S.
// grid 2048, block 64 (1 wave; upper 32 lanes mirror lower for uniform barriers).
// ---------------------------------------------------------------------------
__device__ __forceinline__ float rsum32(float v) {
    v += __shfl_xor(v, 1, 32);
    v += __shfl_xor(v, 2, 32);
    v += __shfl_xor(v, 4, 32);
    v += __shfl_xor(v, 8, 32);
    v += __shfl_xor(v, 16, 32);
    return v;
}
__device__ __forceinline__ float rmax32(float v) {
    v = fmaxf(v, __shfl_xor(v, 1, 32));
    v = fmaxf(v, __shfl_xor(v, 2, 32));
    v = fmaxf(v, __shfl_xor(v, 4, 32));
    v = fmaxf(v, __shfl_xor(v, 8, 32));
    v = fmaxf(v, __shfl_xor(v, 16, 32));
    return v;
}

__global__ __launch_bounds__(64) void k_fwdbwd(const float* __restrict__ Tm,
                                               const int* __restrict__ labels,
                                               float* __restrict__ dp,      // in: dots, out: Pdiff (in place)
                                               float* __restrict__ dTpart) {
    __shared__ __align__(16) float dlds[2048];   // dots row, overwritten by gd during beta
    __shared__ __align__(16) float Ybuf[64][32];
    __shared__ __align__(16) float esbuf[1024];  // pair-hist (float atomics), then hist - E.*S
    __shared__ float xbuf[32];
    __shared__ int labbuf[64];

    const int n = blockIdx.x;
    const int lane = threadIdx.x;
    const int k = lane & 31;

    float* drow = dp + (size_t)n * 2048;

    // stage dots row; zero hist; load labels
    {
        const float4* src = (const float4*)drow;
        float4* dst = (float4*)dlds;
#pragma unroll
        for (int q = 0; q < 8; ++q) dst[lane + q * 64] = src[lane + q * 64];
    }
#pragma unroll
    for (int q = 0; q < 16; ++q) esbuf[lane * 16 + q] = 0.f;
    labbuf[lane] = labels[n * 64 + lane];
    __syncthreads();
    if (lane < 63) atomicAdd(&esbuf[labbuf[lane] * 32 + labbuf[lane + 1]], 1.0f);

    float Ecol[32], Erow[32], Scol[32];
#pragma unroll
    for (int j = 0; j < 32; ++j) {
        Ecol[j] = __expf(Tm[j * 32 + k]);  // E[j][k]
        Erow[j] = __expf(Tm[k * 32 + j]);  // E[k][j]
        Scol[j] = 0.f;
    }

    // ---- beta pass: Y[i] = normalize(B[i]*gd[i]); B[i-1] = E @ Y[i] ----
    float Breg = 1.0f;
    for (int i = 63; i >= 0; --i) {
        float dv = dlds[i * 32 + k];
        float gd = __expf(dv - rmax32(dv));
        if (lane < 32) dlds[i * 32 + k] = gd;  // cache gd for alpha pass
        float yv = Breg * gd;
        float yn = yv * __builtin_amdgcn_rcpf(rsum32(yv));
        if (lane < 32) Ybuf[i][k] = yn;
        __syncthreads();
        if (i > 0) {
            const float4* y4 = (const float4*)(&Ybuf[i][0]);
            float acc = 0.f;
#pragma unroll
            for (int jj = 0; jj < 8; ++jj) {
                float4 y = y4[jj];
                acc += Erow[jj * 4 + 0] * y.x + Erow[jj * 4 + 1] * y.y +
                       Erow[jj * 4 + 2] * y.z + Erow[jj * 4 + 3] * y.w;
            }
            Breg = acc;
        }
    }
    __syncthreads();

    // ---- alpha pass, fused p1 + p2 ----
    float Areg = 1.0f;
    for (int i = 0; i < 64; ++i) {
        float gd = dlds[i * 32 + k];
        // p1 = softmax(alpha+beta+dots) = normalize(A * Y[i])
        float pr = Areg * Ybuf[i][k];
        float p = pr * __builtin_amdgcn_rcpf(rsum32(pr));
        float pd = ((labbuf[i] == k) ? 1.0f : 0.0f) - p;
        if (lane < 32) drow[i * 32 + k] = pd;  // Pdiff overwrites dots in ws
        if (i < 63) {
            float X = Areg * gd;
            float xn = X * __builtin_amdgcn_rcpf(rsum32(X));
            if (lane < 32) xbuf[k] = xn;
            __syncthreads();
            float xb[32];
            {
                const float4* x4 = (const float4*)xbuf;
#pragma unroll
                for (int jj = 0; jj < 8; ++jj) {
                    float4 x = x4[jj];
                    xb[jj * 4 + 0] = x.x; xb[jj * 4 + 1] = x.y;
                    xb[jj * 4 + 2] = x.z; xb[jj * 4 + 3] = x.w;
                }
            }
            float w2 = 0.f;
#pragma unroll
            for (int j = 0; j < 32; ++j) w2 += Ecol[j] * xb[j];  // = A[i+1] (unnorm)
            float yk = Ybuf[i + 1][k];
            float Z = rsum32(w2 * yk);
            float cc = yk * __builtin_amdgcn_rcpf(Z);
#pragma unroll
            for (int j = 0; j < 32; ++j) Scol[j] += xb[j] * cc;
            Areg = w2;
            __syncthreads();  // protect xbuf WAR before next iteration
        }
    }

    // ---- dT partial: hist - E.*S ----
    if (lane < 32) {
#pragma unroll
        for (int j = 0; j < 32; ++j) esbuf[j * 32 + k] -= Ecol[j] * Scol[j];
    }
    __syncthreads();
    float* op = dTpart + (size_t)n * 1024;
#pragma unroll
    for (int q = 0; q < 16; ++q) {
        int idx = q * 64 + lane;
        op[idx] = esbuf[idx];
    }
}

// ---------------------------------------------------------------------------
// K3: dw partials. grid = 256 word-groups x 4 d-chunks; block 256.
// Wave kg owns k0=kg*8; lane owns a d-pair. Accumulates over 8 words x 64 m.
// ---------------------------------------------------------------------------
__global__ __launch_bounds__(256, 4) void k_dw(const float* __restrict__ data,
                                               const float* __restrict__ Pdiff,
                                               float* __restrict__ dwpart) {
    const int g = blockIdx.x >> 2;
    const int c = blockIdx.x & 3;
    const int tid = threadIdx.x;
    const int kg = __builtin_amdgcn_readfirstlane(tid >> 6);
    const int lane = tid & 63;
    const int k0 = kg << 3;
    const int d0 = c * 128 + lane * 2;

    float acc[16];
#pragma unroll
    for (int i = 0; i < 16; ++i) acc[i] = 0.f;

    for (int w = 0; w < 8; ++w) {
        const int nb = (g * 8 + w) * 64;
        const float* dbase = data + (size_t)nb * 512 + d0;
        const float4* pbase = (const float4*)(Pdiff + (size_t)nb * 32);
#pragma unroll 4
        for (int m = 0; m < 64; ++m) {
            float2 dv = *(const float2*)(dbase + m * 512);
            float4 pa = pbase[m * 8 + kg * 2];
            float4 pb = pbase[m * 8 + kg * 2 + 1];
            acc[0] += pa.x * dv.x;  acc[1] += pa.x * dv.y;
            acc[2] += pa.y * dv.x;  acc[3] += pa.y * dv.y;
            acc[4] += pa.z * dv.x;  acc[5] += pa.z * dv.y;
            acc[6] += pa.w * dv.x;  acc[7] += pa.w * dv.y;
            acc[8] += pb.x * dv.x;  acc[9] += pb.x * dv.y;
            acc[10] += pb.y * dv.x; acc[11] += pb.y * dv.y;
            acc[12] += pb.z * dv.x; acc[13] += pb.z * dv.y;
            acc[14] += pb.w * dv.x; acc[15] += pb.w * dv.y;
        }
    }
    float* op = dwpart + (size_t)g * 16384;
#pragma unroll
    for (int kk = 0; kk < 8; ++kk) {
        *(float2*)(op + (k0 + kk) * 512 + d0) = make_float2(acc[kk * 2], acc[kk * 2 + 1]);
    }
}

// ---------------------------------------------------------------------------
// K4: reduce partials, scale by 1/N, write d_out (meandw || meandT)
// ---------------------------------------------------------------------------
__global__ __launch_bounds__(256) void k_final(const float* __restrict__ dwpart,
                                               const float* __restrict__ dTpart,
                                               float* __restrict__ out) {
    const int b = blockIdx.x, t = threadIdx.x;
    const float inv = 1.0f / 2048.0f;
    if (b < 64) {
        const int idx = b * 256 + t;
        float s = 0.f;
#pragma unroll 8
        for (int g = 0; g < 256; ++g) s += dwpart[(size_t)g * 16384 + idx];
        out[idx] = s * inv;
    } else {
        const int idx = (b - 64) * 256 + t;
        float s = 0.f;
#pragma unroll 8
        for (int nn = 0; nn < 2048; ++nn) s += dTpart[(size_t)nn * 1024 + idx];
        out[16384 + idx] = s * inv;
    }
}

// ---------------------------------------------------------------------------
// ws layout (floats): [0,4194304) dots->Pdiff | [4194304,6291456) dT partials
//                     [6291456,10485760) dw partials   (~42 MB total)
// ---------------------------------------------------------------------------
extern "C" void kernel_launch(void* const* d_in, const int* in_sizes, int n_in,
                              void* d_out, int out_size, void* d_ws, size_t ws_size,
                              hipStream_t stream) {
    const float* W = (const float*)d_in[0];
    const float* Tm = (const float*)d_in[1];
    const float* data = (const float*)d_in[2];
    const int* labels = (const int*)d_in[3];
    float* out = (float*)d_out;
    float* ws = (float*)d_ws;

    float* dots = ws;                  // 2048*64*32
    float* dTpart = ws + 4194304;      // 2048*1024
    float* dwpart = ws + 6291456;      // 256*16384

    hipLaunchKernelGGL(k_dots, dim3(NW), dim3(256), 0, stream, data, W, dots);
    hipLaunchKernelGGL(k_fwdbwd, dim3(NW), dim3(64), 0, stream, Tm, labels, dots, dTpart);
    hipLaunchKernelGGL(k_dw, dim3(1024), dim3(256), 0, stream, data, dots, dwpart);
    hipLaunchKernelGGL(k_final, dim3(68), dim3(256), 0, stream, dwpart, dTpart, out);
}

// Round 2
// 573.709 us; speedup vs baseline: 1.0141x; 1.0141x over previous
//
#include <hip/hip_runtime.h>
#include <math.h>

// ---------------------------------------------------------------------------
// K1: dots[r][k] = sum_d data[r][d] * W[k][d],  r = n*64+m in [0,131072)
// 64 rows/block, d-chunks of 64 floats double-buffered in LDS (XOR-swizzled),
// coalesced global loads, W via wave-uniform scalar loads.
// ---------------------------------------------------------------------------
__global__ __launch_bounds__(256) void k_dots(const float* __restrict__ data,
                                              const float* __restrict__ W,
                                              float* __restrict__ dots) {
    __shared__ float4 ch[2][64][16];   // 32 KB double-buffered data chunk
    __shared__ float dt[64][33];       // output transpose buffer
    const int tid = threadIdx.x;
    const int row0 = blockIdx.x * 64;
    const int lane = tid & 63;
    const int k0 = __builtin_amdgcn_readfirstlane((tid >> 6) << 3);
    const float4* d4 = (const float4*)data;
    const float4* w4 = (const float4*)W;

    float4 st[4];
    // prologue: stage chunk 0
#pragma unroll
    for (int it = 0; it < 4; ++it) {
        int f = tid + it * 256; int r = f >> 4, dq = f & 15;
        st[it] = d4[(size_t)(row0 + r) * 128 + dq];
    }
#pragma unroll
    for (int it = 0; it < 4; ++it) {
        int f = tid + it * 256; int r = f >> 4, dq = f & 15;
        ch[0][r][dq ^ (r & 15)] = st[it];
    }
    __syncthreads();

    float acc[8];
#pragma unroll
    for (int i = 0; i < 8; ++i) acc[i] = 0.f;

    for (int c = 0; c < 8; ++c) {
        const int cur = c & 1;
        if (c < 7) {  // issue next chunk's loads early (hide under compute)
#pragma unroll
            for (int it = 0; it < 4; ++it) {
                int f = tid + it * 256; int r = f >> 4, dq = f & 15;
                st[it] = d4[(size_t)(row0 + r) * 128 + (c + 1) * 16 + dq];
            }
        }
#pragma unroll
        for (int dq = 0; dq < 16; ++dq) {
            float4 dv = ch[cur][lane][dq ^ (lane & 15)];
#pragma unroll
            for (int kk = 0; kk < 8; ++kk) {
                float4 wv = w4[(k0 + kk) * 128 + c * 16 + dq];
                acc[kk] += dv.x * wv.x + dv.y * wv.y + dv.z * wv.z + dv.w * wv.w;
            }
        }
        __syncthreads();
        if (c < 7) {
#pragma unroll
            for (int it = 0; it < 4; ++it) {
                int f = tid + it * 256; int r = f >> 4, dq = f & 15;
                ch[cur ^ 1][r][dq ^ (r & 15)] = st[it];
            }
        }
        __syncthreads();
    }
    // transpose to row-major [row][k] and write coalesced
#pragma unroll
    for (int kk = 0; kk < 8; ++kk) dt[lane][k0 + kk] = acc[kk];
    __syncthreads();
    float* outp = dots + (size_t)row0 * 32;
    for (int q = tid; q < 2048; q += 256) outp[q] = dt[q >> 5][q & 31];
}

// ---------------------------------------------------------------------------
// K2: per-word forward-backward, 2 waves/word (alpha || beta), scaled linear
// space. Stores Un[i]=normalize(A*gd), M[i]=unnorm beta matvec, s[i]=sum(M[i]).
// p1 ~ Un*M (normalizer Z); p2 rank-1: S += Un * (gd*M/s)^T / Z.
// dTpart = pair-hist - E .* S.
// ---------------------------------------------------------------------------
__device__ __forceinline__ float rsum32(float v) {
    v += __shfl_xor(v, 1, 32); v += __shfl_xor(v, 2, 32);
    v += __shfl_xor(v, 4, 32); v += __shfl_xor(v, 8, 32);
    v += __shfl_xor(v, 16, 32);
    return v;
}
__device__ __forceinline__ float rmax32(float v) {
    v = fmaxf(v, __shfl_xor(v, 1, 32)); v = fmaxf(v, __shfl_xor(v, 2, 32));
    v = fmaxf(v, __shfl_xor(v, 4, 32)); v = fmaxf(v, __shfl_xor(v, 8, 32));
    v = fmaxf(v, __shfl_xor(v, 16, 32));
    return v;
}

__global__ __launch_bounds__(128) void k_fwdbwd(const float* __restrict__ Tm,
                                                const int* __restrict__ labels,
                                                float* __restrict__ dp,      // in: dots, out: Pdiff
                                                float* __restrict__ dTpart) {
    __shared__ __align__(16) float gdb[2048];  // dots -> gd
    __shared__ __align__(16) float Unb[2048];
    __shared__ __align__(16) float Mb[2048];
    __shared__ float ssum[64];
    __shared__ float es[1024];
    __shared__ float Sb[1024];
    __shared__ float wtmp[32];
    __shared__ int lab[64];

    const int n = blockIdx.x;
    const int tid = threadIdx.x;
    const int wv = tid >> 6;       // 0: alpha, 1: beta
    const int lane = tid & 63;
    const int k = tid & 31;
    const int hw = tid >> 5;       // half-wave id 0..3
    float* drow = dp + (size_t)n * 2048;

    // stage dots row, zero accumulators, load labels
    {
        const float4* src = (const float4*)drow;
        float4* dst = (float4*)gdb;
#pragma unroll
        for (int i = 0; i < 4; ++i) dst[tid + i * 128] = src[tid + i * 128];
    }
#pragma unroll
    for (int i = 0; i < 8; ++i) { es[tid * 8 + i] = 0.f; Sb[tid * 8 + i] = 0.f; }
    if (tid < 64) lab[tid] = labels[n * 64 + tid];
    __syncthreads();

    // gd[i][k] = exp(dots - rowmax); 4 half-waves x 16 positions
#pragma unroll
    for (int ii = 0; ii < 16; ++ii) {
        int i = hw * 16 + ii;
        float d = gdb[i * 32 + k];
        float mx = rmax32(d);
        gdb[i * 32 + k] = __expf(d - mx);
    }
    if (tid < 63) atomicAdd(&es[lab[tid] * 32 + lab[tid + 1]], 1.0f);
    __syncthreads();

    if (wv == 0) {
        // ---- alpha forward ----
        float Ecol[32];
#pragma unroll
        for (int j = 0; j < 32; ++j) Ecol[j] = __expf(Tm[j * 32 + k]);
        float Areg = 1.f;
        for (int i = 0; i < 64; ++i) {
            float t = Areg * gdb[i * 32 + k];
            float un = t * __builtin_amdgcn_rcpf(rsum32(t));
            Unb[i * 32 + k] = un;
            asm volatile("s_waitcnt lgkmcnt(0)" ::: "memory");
            if (i < 63) {
                const float4* uv = (const float4*)(&Unb[i * 32]);
                float a = 0.f;
#pragma unroll
                for (int j8 = 0; j8 < 8; ++j8) {
                    float4 u = uv[j8];
                    a += Ecol[j8 * 4 + 0] * u.x + Ecol[j8 * 4 + 1] * u.y +
                         Ecol[j8 * 4 + 2] * u.z + Ecol[j8 * 4 + 3] * u.w;
                }
                Areg = a;
            }
        }
    } else {
        // ---- beta backward ----
        float Erow[32];
#pragma unroll
        for (int j = 0; j < 32; ++j) Erow[j] = __expf(Tm[k * 32 + j]);
        Mb[63 * 32 + k] = 1.f;
        if (lane == 0) ssum[63] = 32.f;
        float Mreg = 1.f, scur = 32.f;
        for (int i = 63; i > 0; --i) {
            float ww = gdb[i * 32 + k] * Mreg * __builtin_amdgcn_rcpf(scur);
            wtmp[k] = ww;
            asm volatile("s_waitcnt lgkmcnt(0)" ::: "memory");
            const float4* wvv = (const float4*)wtmp;
            float m2 = 0.f;
#pragma unroll
            for (int j8 = 0; j8 < 8; ++j8) {
                float4 u = wvv[j8];
                m2 += Erow[j8 * 4 + 0] * u.x + Erow[j8 * 4 + 1] * u.y +
                      Erow[j8 * 4 + 2] * u.z + Erow[j8 * 4 + 3] * u.w;
            }
            float s2 = rsum32(m2);
            Mb[(i - 1) * 32 + k] = m2;
            if (lane == 0) ssum[i - 1] = s2;
            Mreg = m2; scur = s2;
        }
    }
    __syncthreads();

    // ---- p-phase: 4 half-waves x 16 positions; fused p1 + rank-1 S ----
    float Scol[32];
#pragma unroll
    for (int j = 0; j < 32; ++j) Scol[j] = 0.f;
    const int i0 = hw * 16;
    for (int ii = 0; ii < 16; ++ii) {
        int i = i0 + ii;
        float un = Unb[i * 32 + k];
        float mm = Mb[i * 32 + k];
        float t = un * mm;
        float Z = rsum32(t);
        float rZ = __builtin_amdgcn_rcpf(Z);
        float pd = ((lab[i] == k) ? 1.f : 0.f) - t * rZ;
        drow[i * 32 + k] = pd;   // Pdiff overwrites dots
        if (i < 63) {
            float q = gdb[(i + 1) * 32 + k] * Mb[(i + 1) * 32 + k] *
                      __builtin_amdgcn_rcpf(ssum[i + 1]);
            float f = q * rZ;
            const float4* uv = (const float4*)(&Unb[i * 32]);
#pragma unroll
            for (int j8 = 0; j8 < 8; ++j8) {
                float4 u = uv[j8];
                Scol[j8 * 4 + 0] += u.x * f; Scol[j8 * 4 + 1] += u.y * f;
                Scol[j8 * 4 + 2] += u.z * f; Scol[j8 * 4 + 3] += u.w * f;
            }
        }
    }
#pragma unroll
    for (int j = 0; j < 32; ++j) atomicAdd(&Sb[j * 32 + k], Scol[j]);
    __syncthreads();

    float* op = dTpart + (size_t)n * 1024;
#pragma unroll
    for (int e = 0; e < 8; ++e) {
        int idx = tid * 8 + e;
        op[idx] = es[idx] - __expf(Tm[idx]) * Sb[idx];
    }
}

// ---------------------------------------------------------------------------
// K3: dw partials = Pdiff^T @ data. grid = 256 word-groups x 2 d-halves.
// Lane owns float4 of d (coalesced 1KB/wave), wave owns 8 k (scalar Pdiff).
// ---------------------------------------------------------------------------
__global__ __launch_bounds__(256) void k_dw(const float* __restrict__ data,
                                            const float* __restrict__ Pd,
                                            float* __restrict__ dwp) {
    const int g = blockIdx.x >> 1;
    const int half = blockIdx.x & 1;
    const int tid = threadIdx.x;
    const int kg = __builtin_amdgcn_readfirstlane(tid >> 6);
    const int lane = tid & 63;
    const int k0 = kg << 3;
    const int d0 = half * 256 + lane * 4;

    float4 acc[8];
#pragma unroll
    for (int i = 0; i < 8; ++i) acc[i] = make_float4(0.f, 0.f, 0.f, 0.f);

    const size_t rbase = (size_t)g * 512;
#pragma unroll 4
    for (int r = 0; r < 512; ++r) {
        float4 dv = *(const float4*)(data + (rbase + r) * 512 + d0);
        const float4* pp = (const float4*)(Pd + (rbase + r) * 32 + k0);
        float4 pa = pp[0], pb = pp[1];
        acc[0].x += pa.x * dv.x; acc[0].y += pa.x * dv.y; acc[0].z += pa.x * dv.z; acc[0].w += pa.x * dv.w;
        acc[1].x += pa.y * dv.x; acc[1].y += pa.y * dv.y; acc[1].z += pa.y * dv.z; acc[1].w += pa.y * dv.w;
        acc[2].x += pa.z * dv.x; acc[2].y += pa.z * dv.y; acc[2].z += pa.z * dv.z; acc[2].w += pa.z * dv.w;
        acc[3].x += pa.w * dv.x; acc[3].y += pa.w * dv.y; acc[3].z += pa.w * dv.z; acc[3].w += pa.w * dv.w;
        acc[4].x += pb.x * dv.x; acc[4].y += pb.x * dv.y; acc[4].z += pb.x * dv.z; acc[4].w += pb.x * dv.w;
        acc[5].x += pb.y * dv.x; acc[5].y += pb.y * dv.y; acc[5].z += pb.y * dv.z; acc[5].w += pb.y * dv.w;
        acc[6].x += pb.z * dv.x; acc[6].y += pb.z * dv.y; acc[6].z += pb.z * dv.z; acc[6].w += pb.z * dv.w;
        acc[7].x += pb.w * dv.x; acc[7].y += pb.w * dv.y; acc[7].z += pb.w * dv.z; acc[7].w += pb.w * dv.w;
    }
    float* op = dwp + (size_t)g * 16384;
#pragma unroll
    for (int kk = 0; kk < 8; ++kk)
        *(float4*)(op + (k0 + kk) * 512 + d0) = acc[kk];
}

// ---------------------------------------------------------------------------
// K4: reduce partials, scale 1/N. blocks 0..255: dw (64 outs each);
// blocks 256..319: dT (16 outs each).
// ---------------------------------------------------------------------------
__global__ __launch_bounds__(256) void k_final(const float* __restrict__ dwp,
                                               const float* __restrict__ dTp,
                                               float* __restrict__ out) {
    __shared__ float red[256];
    const int b = blockIdx.x, t = threadIdx.x;
    const float inv = 1.0f / 2048.0f;
    if (b < 256) {
        const int q = t >> 6, ol = t & 63;
        const int oi = b * 64 + ol;
        float s = 0.f;
#pragma unroll 4
        for (int j = 0; j < 64; ++j) s += dwp[(size_t)(q * 64 + j) * 16384 + oi];
        red[t] = s;
        __syncthreads();
        if (t < 64) out[b * 64 + t] = (red[t] + red[t + 64] + red[t + 128] + red[t + 192]) * inv;
    } else {
        const int ol = t >> 4, q = t & 15;
        const int oi = (b - 256) * 16 + ol;
        float s = 0.f;
#pragma unroll 4
        for (int j = 0; j < 128; ++j) s += dTp[(size_t)(q * 128 + j) * 1024 + oi];
        s += __shfl_xor(s, 1, 16); s += __shfl_xor(s, 2, 16);
        s += __shfl_xor(s, 4, 16); s += __shfl_xor(s, 8, 16);
        if (q == 0) out[16384 + oi] = s * inv;
    }
}

// ---------------------------------------------------------------------------
// ws layout (floats): [0,4194304) dots->Pdiff | [4194304,6291456) dT partials
//                     [6291456,10485760) dw partials   (~42 MB total)
// ---------------------------------------------------------------------------
extern "C" void kernel_launch(void* const* d_in, const int* in_sizes, int n_in,
                              void* d_out, int out_size, void* d_ws, size_t ws_size,
                              hipStream_t stream) {
    const float* W = (const float*)d_in[0];
    const float* Tm = (const float*)d_in[1];
    const float* data = (const float*)d_in[2];
    const int* labels = (const int*)d_in[3];
    float* out = (float*)d_out;
    float* ws = (float*)d_ws;

    float* dots = ws;                  // 2048*64*32
    float* dTpart = ws + 4194304;      // 2048*1024
    float* dwpart = ws + 6291456;      // 256*16384

    hipLaunchKernelGGL(k_dots, dim3(2048), dim3(256), 0, stream, data, W, dots);
    hipLaunchKernelGGL(k_fwdbwd, dim3(2048), dim3(128), 0, stream, Tm, labels, dots, dTpart);
    hipLaunchKernelGGL(k_dw, dim3(512), dim3(256), 0, stream, data, dots, dwpart);
    hipLaunchKernelGGL(k_final, dim3(320), dim3(256), 0, stream, dwpart, dTpart, out);
}